// Round 7
// baseline (101.604 us; speedup 1.0000x reference)
//
#include <hip/hip_runtime.h>

#define N_ROWS 16384
#define L_DIM  4096
#define CG     16                  // locations per block
#define JT     1024                // output-j columns per block
#define CHUNK  256                 // j-rows per pipeline chunk
#define NCHUNK (JT / CHUNK)        // 4
#define PITCH  (CHUNK + 4)         // 260 floats: 16B-aligned, conflict-free b128
#define CAP    512                 // list capacity (bucket ~Poisson(64), max ~110)

typedef float f32x4 __attribute__((ext_vector_type(4)));

// out[i, j] = z[i, w[i]] * W[j, w[i]] + b[j]
// Block (g, t): locations l0=g*CG.., j-range j0=t*JT..
// R7: scan first, then 4-chunk double-buffered stage/stream pipeline.
// Goal: first store ~3us into the block (was ~10), stores continuous after.
// 37.4KB LDS -> 4 blocks/CU -> all 1024 blocks co-resident (one round).
__global__ __launch_bounds__(256, 4) void pnet_fused(
    const int* __restrict__ w,
    const float* __restrict__ z,
    const float* __restrict__ W,
    const float* __restrict__ b,
    float* __restrict__ out)
{
    __shared__ float tile[2][CG * PITCH];   // 2 x 16.6KB chunk tiles
    __shared__ int   list[CAP];             // i | (c<<16)
    __shared__ float zlist[CAP];
    __shared__ int   cnt;

    const int tid  = threadIdx.x;
    const int l0   = blockIdx.x * CG;
    const int j0   = blockIdx.y * JT;
    const int wid  = tid >> 6;
    const int lane = tid & 63;

    if (tid == 0) cnt = 0;

    // per-lane bias fragment for each chunk: j = j0 + cc*CHUNK + lane*4
    f32x4 bb[NCHUNK];
    #pragma unroll
    for (int cc = 0; cc < NCHUNK; ++cc)
        bb[cc] = *(const f32x4*)&b[j0 + cc * CHUNK + lane * 4];

    __syncthreads();  // cnt ready

    // ---- scan w[] once: append packed entries (L2-broadcast reads, no gathers) ----
    #pragma unroll 4
    for (int s = 0; s < N_ROWS / 1024; ++s) {
        const int i0  = s * 1024 + tid * 4;
        const int4 wv = *(const int4*)&w[i0];
        const int vals[4] = {wv.x, wv.y, wv.z, wv.w};
        #pragma unroll
        for (int e = 0; e < 4; ++e) {
            const unsigned c = (unsigned)(vals[e] - l0);
            if (c < CG) {
                const int pos = atomicAdd(&cnt, 1);
                if (pos < CAP) list[pos] = (i0 + e) | ((int)c << 16);
            }
        }
    }
    __syncthreads();  // list ready
    const int n     = cnt;
    const int nmain = n < CAP ? n : CAP;

    // ---- coop zw gather: all loads in flight at once (overlaps chunk-0 stage) ----
    for (int e = tid; e < nmain; e += 256) {
        const int ent = list[e];
        zlist[e] = z[(unsigned)((ent & 0xFFFF) * L_DIM) + (unsigned)(ent >> 16) + l0];
    }

    // ---- stage macro: chunk cc -> buf (coalesced nt float4 reads, transposed LDS writes) ----
#define STAGE(cc, buf)                                                              \
    {                                                                               \
        const int q     = tid & 3;                                                  \
        const int rbase = tid >> 2;                                                 \
        _Pragma("unroll")                                                           \
        for (int it = 0; it < CHUNK / 64; ++it) {                                   \
            const int r = rbase + it * 64;                                          \
            const f32x4 v = __builtin_nontemporal_load(                             \
                (const f32x4*)&W[(size_t)(j0 + (cc) * CHUNK + r) * L_DIM + l0 + 4 * q]); \
            tile[buf][(4 * q + 0) * PITCH + r] = v.x;                               \
            tile[buf][(4 * q + 1) * PITCH + r] = v.y;                               \
            tile[buf][(4 * q + 2) * PITCH + r] = v.z;                               \
            tile[buf][(4 * q + 3) * PITCH + r] = v.w;                               \
        }                                                                           \
    }

    STAGE(0, 0);
    __syncthreads();  // zlist + tile[0] ready

    // ---- pipeline: stage chunk cc+1 while streaming chunk cc ----
    for (int cc = 0; cc < NCHUNK; ++cc) {
        const int cur = cc & 1;
        if (cc + 1 < NCHUNK) STAGE(cc + 1, cur ^ 1);

        for (int e = wid; e < nmain; e += 4) {
            const int   ent = list[e];
            const int   i   = ent & 0xFFFF;
            const int   c   = ent >> 16;
            const float zw  = zlist[e];
            const f32x4 wv4 = *(const f32x4*)&tile[cur][c * PITCH + lane * 4];
            f32x4 o;
            o.x = fmaf(zw, wv4.x, bb[cc].x);
            o.y = fmaf(zw, wv4.y, bb[cc].y);
            o.z = fmaf(zw, wv4.z, bb[cc].z);
            o.w = fmaf(zw, wv4.w, bb[cc].w);
            __builtin_nontemporal_store(o,
                (f32x4*)&out[(unsigned)(i * L_DIM) + j0 + cc * CHUNK + lane * 4]);
        }
        __syncthreads();  // next buf staged; cur free for restage
    }

    // ---- overflow fallback (unreachable for this input; correct for any input) ----
    if (n > CAP) {
        for (int p = 0; p < N_ROWS / CAP; ++p) {
            __syncthreads();
            if (tid == 0) cnt = 0;
            __syncthreads();
            const int i0  = p * CAP + tid * 2;
            const int2 wv = *(const int2*)&w[i0];
            const int vals[2] = {wv.x, wv.y};
            #pragma unroll
            for (int e = 0; e < 2; ++e) {
                const unsigned c = (unsigned)(vals[e] - l0);
                if (c < CG) {
                    const int pos = atomicAdd(&cnt, 1);   // <= CAP per pass
                    list[pos]  = (i0 + e) | ((int)c << 16);
                    zlist[pos] = z[(unsigned)((i0 + e) * L_DIM) + vals[e]];
                }
            }
            __syncthreads();
            const int np = cnt;
            for (int cc = 0; cc < NCHUNK; ++cc) {
                STAGE(cc, 0);
                __syncthreads();
                for (int e = wid; e < np; e += 4) {
                    const int   ent = list[e];
                    const int   i   = ent & 0xFFFF;
                    const int   c   = ent >> 16;
                    const float zw  = zlist[e];
                    const f32x4 wv4 = *(const f32x4*)&tile[0][c * PITCH + lane * 4];
                    f32x4 o;
                    o.x = fmaf(zw, wv4.x, bb[cc].x);
                    o.y = fmaf(zw, wv4.y, bb[cc].y);
                    o.z = fmaf(zw, wv4.z, bb[cc].z);
                    o.w = fmaf(zw, wv4.w, bb[cc].w);
                    *(f32x4*)&out[(unsigned)(i * L_DIM) + j0 + cc * CHUNK + lane * 4] = o;
                }
                __syncthreads();
            }
        }
    }
#undef STAGE
}

extern "C" void kernel_launch(void* const* d_in, const int* in_sizes, int n_in,
                              void* d_out, int out_size, void* d_ws, size_t ws_size,
                              hipStream_t stream) {
    const int*   w = (const int*)d_in[0];
    const float* z = (const float*)d_in[1];
    const float* W = (const float*)d_in[2];
    const float* b = (const float*)d_in[3];
    float* out = (float*)d_out;

    dim3 grid(L_DIM / CG, L_DIM / JT);   // (256, 4) = 1024 blocks, all co-resident
    pnet_fused<<<grid, 256, 0, stream>>>(w, z, W, b, out);
}

// Round 8
// 75.910 us; speedup vs baseline: 1.3385x; 1.3385x over previous
//
#include <hip/hip_runtime.h>

#define N_ROWS 16384
#define L_DIM  4096
#define CG     16                 // locations per block
#define JT     1024               // output-j columns per block
#define NBKT   (L_DIM / CG)       // 256
#define PITCH  (JT + 4)           // 16B-aligned rows; stage writes 2-way banked (free)
#define CAP    1792               // list capacity (bucket ~Poisson(64), max ~110)

typedef float f32x4 __attribute__((ext_vector_type(4)));

// out[i, j] = z[i, w[i]] * W[j, w[i]] + b[j]
// R8 = R5 structure + NON-TEMPORAL output stores (single-variable change).
// Rationale: 268MB of streaming stores were evicting w/z/W from L2; out lines
// are never re-read, so keep them out of L2 entirely.
__global__ __launch_bounds__(256, 2) void pnet_fused(
    const int* __restrict__ w,
    const float* __restrict__ z,
    const float* __restrict__ W,
    const float* __restrict__ b,
    float* __restrict__ out)
{
    __shared__ float tile[CG * PITCH];   // tile[c*PITCH + r] = W[j0+r][l0+c]
    __shared__ int   list[CAP];          // i | (c<<16)
    __shared__ float zlist[CAP];
    __shared__ int   cnt;

    const int tid  = threadIdx.x;
    const int l0   = blockIdx.x * CG;
    const int j0   = blockIdx.y * JT;
    const int wid  = tid >> 6;
    const int lane = tid & 63;

    if (tid == 0) cnt = 0;

    f32x4 bb[4];
    #pragma unroll
    for (int k = 0; k < 4; ++k)
        bb[k] = *(const f32x4*)&b[j0 + (k * 64 + lane) * 4];

    __syncthreads();  // cnt ready

    // ---- stage W tile: coalesced float4 HBM reads (one 64B line per W row),
    //      transposed scalar LDS writes ----
    {
        const int q     = tid & 3;
        const int rbase = tid >> 2;
        #pragma unroll
        for (int it = 0; it < JT / 64; ++it) {
            const int r = rbase + it * 64;
            const f32x4 v = *(const f32x4*)&W[(size_t)(j0 + r) * L_DIM + l0 + 4 * q];
            tile[(4 * q + 0) * PITCH + r] = v.x;
            tile[(4 * q + 1) * PITCH + r] = v.y;
            tile[(4 * q + 2) * PITCH + r] = v.z;
            tile[(4 * q + 3) * PITCH + r] = v.w;
        }
    }

    // ---- scan w[] once: append packed entries (L2-fast, no gathers) ----
    #pragma unroll
    for (int s = 0; s < N_ROWS / 1024; ++s) {
        const int i0  = s * 1024 + tid * 4;
        const int4 wv = *(const int4*)&w[i0];
        const int vals[4] = {wv.x, wv.y, wv.z, wv.w};
        #pragma unroll
        for (int e = 0; e < 4; ++e) {
            const unsigned c = (unsigned)(vals[e] - l0);
            if (c < CG) {
                const int pos = atomicAdd(&cnt, 1);
                if (pos < CAP) list[pos] = (i0 + e) | ((int)c << 16);
            }
        }
    }

    __syncthreads();  // tile + list ready
    const int n     = cnt;
    const int nmain = n < CAP ? n : CAP;

    // ---- cooperative zw gather: every entry's load in flight simultaneously ----
    for (int e = tid; e < nmain; e += 256) {
        const int ent = list[e];
        const int i   = ent & 0xFFFF;
        const int c   = ent >> 16;
        zlist[e] = z[(size_t)i * L_DIM + l0 + c];
    }
    __syncthreads();  // zlist ready

    // ---- stream matched rows; no barriers, no atomics; nt stores ----
    for (int e = wid; e < nmain; e += 4) {
        const int   ent = list[e];
        const int   i   = ent & 0xFFFF;
        const int   c   = ent >> 16;
        const float zw  = zlist[e];
        const float* __restrict__ trow = &tile[c * PITCH];
        float*       __restrict__ orow = &out[(size_t)i * L_DIM + j0];
        #pragma unroll
        for (int k = 0; k < 4; ++k) {
            const int jj = (k * 64 + lane) * 4;
            const f32x4 wv4 = *(const f32x4*)&trow[jj];   // ds_read_b128, conflict-free
            f32x4 o;
            o.x = fmaf(zw, wv4.x, bb[k].x);
            o.y = fmaf(zw, wv4.y, bb[k].y);
            o.z = fmaf(zw, wv4.z, bb[k].z);
            o.w = fmaf(zw, wv4.w, bb[k].w);
            __builtin_nontemporal_store(o, (f32x4*)&orow[jj]);  // coalesced, L2-bypass
        }
    }

    // ---- overflow fallback (unreachable for this input; correct for any input) ----
    if (n > CAP) {
        for (int p = 0; p < N_ROWS / 1024; ++p) {
            __syncthreads();
            if (tid == 0) cnt = 0;
            __syncthreads();
            const int i0  = p * 1024 + tid * 4;
            const int4 wv = *(const int4*)&w[i0];
            const int vals[4] = {wv.x, wv.y, wv.z, wv.w};
            #pragma unroll
            for (int e = 0; e < 4; ++e) {
                const unsigned c = (unsigned)(vals[e] - l0);
                if (c < CG) {
                    const int pos = atomicAdd(&cnt, 1);   // <=1024 per pass <= CAP
                    list[pos]  = (i0 + e) | ((int)c << 16);
                    zlist[pos] = z[(size_t)(i0 + e) * L_DIM + vals[e]];
                }
            }
            __syncthreads();
            const int np = cnt;
            for (int e = wid; e < np; e += 4) {
                const int   ent = list[e];
                const int   i   = ent & 0xFFFF;
                const int   c   = ent >> 16;
                const float zw  = zlist[e];
                const float* __restrict__ trow = &tile[c * PITCH];
                float*       __restrict__ orow = &out[(size_t)i * L_DIM + j0];
                #pragma unroll
                for (int k = 0; k < 4; ++k) {
                    const int jj = (k * 64 + lane) * 4;
                    const f32x4 wv4 = *(const f32x4*)&trow[jj];
                    f32x4 o;
                    o.x = fmaf(zw, wv4.x, bb[k].x);
                    o.y = fmaf(zw, wv4.y, bb[k].y);
                    o.z = fmaf(zw, wv4.z, bb[k].z);
                    o.w = fmaf(zw, wv4.w, bb[k].w);
                    __builtin_nontemporal_store(o, (f32x4*)&orow[jj]);
                }
            }
        }
    }
}

extern "C" void kernel_launch(void* const* d_in, const int* in_sizes, int n_in,
                              void* d_out, int out_size, void* d_ws, size_t ws_size,
                              hipStream_t stream) {
    const int*   w = (const int*)d_in[0];
    const float* z = (const float*)d_in[1];
    const float* W = (const float*)d_in[2];
    const float* b = (const float*)d_in[3];
    float* out = (float*)d_out;

    dim3 grid(NBKT, L_DIM / JT);   // (256, 4) = 1024 blocks
    pnet_fused<<<grid, 256, 0, stream>>>(w, z, W, b, out);
}